// Round 6
// baseline (1285.123 us; speedup 1.0000x reference)
//
#include <hip/hip_runtime.h>
#include <math.h>

// Problem constants
#define kH  1024
#define kB  64
#define kS  256
#define kV  10000
#define kH3 3072

typedef unsigned long long u64;

// ---------------- helpers ----------------
__device__ __forceinline__ float warp_sum(float v) {
#pragma unroll
  for (int off = 32; off > 0; off >>= 1) v += __shfl_down(v, off, 64);
  return v;  // valid on lane 0
}
__device__ __forceinline__ float warp_max_all(float v) {
#pragma unroll
  for (int off = 32; off > 0; off >>= 1) v = fmaxf(v, __shfl_xor(v, off, 64));
  return v;
}
__device__ __forceinline__ float warp_sum_all(float v) {
#pragma unroll
  for (int off = 32; off > 0; off >>= 1) v += __shfl_xor(v, off, 64);
  return v;
}
__device__ __forceinline__ float sigmoidf_(float x) {
  return __fdividef(1.0f, 1.0f + __expf(-x));
}
__device__ __forceinline__ float tanhf_(float x) {
  const float t = __expf(-2.0f * fabsf(x));
  const float r = __fdividef(1.0f - t, 1.0f + t);
  return copysignf(r, x);
}
__device__ __forceinline__ u64 ld_slot(const u64* p) {
  return __hip_atomic_load(p, __ATOMIC_RELAXED, __HIP_MEMORY_SCOPE_AGENT);
}
__device__ __forceinline__ void st_slot(u64* p, u64 v) {
  __hip_atomic_store(p, v, __ATOMIC_RELAXED, __HIP_MEMORY_SCOPE_AGENT);
}

// ================== Launch A: gi (768 blocks) || w2h (256 blocks) =========
// gi:  GI = emb[seq] @ W_ih^T + b_ih   (independent of w2h)
// w2h: w2h[k] = sum_h v_attn[h] * W_attn[h][H+k]  (softmax shift-invariance
//      kills the h_bc half of cat and b_attn)
__global__ __launch_bounds__(256) void k_pre(const int* __restrict__ seq,
    const float* __restrict__ emb, const float* __restrict__ W_ih,
    const float* __restrict__ b_ih, const float* __restrict__ W_attn,
    const float* __restrict__ v_attn, float* __restrict__ GI,
    float* __restrict__ w2h) {
  __shared__ float4 red[256];
  if (blockIdx.x < 768) {
    // ---- gi role: one wave per output row r, loop over t ----
    const int lane = threadIdx.x & 63;
    const int r = blockIdx.x * 4 + (threadIdx.x >> 6);
    const float4* wp = (const float4*)(W_ih + (size_t)r * kH) + lane * 4;
    const float4 w0 = wp[0], w1 = wp[1], w2 = wp[2], w3 = wp[3];
    const float br = b_ih[r];
    for (int t = 0; t < kB; ++t) {
      const int tok = seq[t];
      const float4* xp = (const float4*)(emb + (size_t)tok * kH) + lane * 4;
      const float4 x0 = xp[0], x1 = xp[1], x2 = xp[2], x3 = xp[3];
      float acc = w0.x*x0.x + w0.y*x0.y + w0.z*x0.z + w0.w*x0.w;
      acc += w1.x*x1.x + w1.y*x1.y + w1.z*x1.z + w1.w*x1.w;
      acc += w2.x*x2.x + w2.y*x2.y + w2.z*x2.z + w2.w*x2.w;
      acc += w3.x*x3.x + w3.y*x3.y + w3.z*x3.z + w3.w*x3.w;
      acc = warp_sum(acc);
      if (lane == 0) GI[(size_t)t * kH3 + r] = acc + br;
    }
  } else {
    // ---- w2h role ----
    const int t  = threadIdx.x;
    const int wb = blockIdx.x - 768;
    const int k0 = kH + wb * 4;  // absolute column in W_attn
    float ax = 0, ay = 0, az = 0, aw = 0;
    for (int h = t; h < kH; h += 256) {
      const float vh = v_attn[h];
      const float4 wq = *(const float4*)(W_attn + (size_t)h * 2048 + k0);
      ax += vh * wq.x; ay += vh * wq.y; az += vh * wq.z; aw += vh * wq.w;
    }
    red[t] = make_float4(ax, ay, az, aw);
    __syncthreads();
    for (int s = 128; s > 0; s >>= 1) {
      if (t < s) {
        const float4 a = red[t], b = red[t + s];
        red[t] = make_float4(a.x + b.x, a.y + b.y, a.z + b.z, a.w + b.w);
      }
      __syncthreads();
    }
    if (t == 0) *(float4*)(w2h + wb * 4) = red[0];
  }
}

// ================== Launch B: mega =======================================
// Roles by blockIdx: gru [0,256) | scores [256,4352) | ctx2 [4352,4416) |
// concat [4416,4544).  All blocks reserve 57344 B LDS (union of role needs)
// -> exactly 2 blocks/CU -> 512 resident slots.
// Spinning blocks: gru 256 + ctx2 64 + concat 128 = 448 <= 512, so all
// spinners are always placeable plus >=64 slots for the finite scores
// blocks to trickle through -> progress under ANY dispatch order.
//
// Tagged-u64 dataflow (single writer per slot, data rides in the atomic
// word, relaxed agent scope, ws poison 0xAAAAAAAA never matches tags):
//   STEP[t][j]  tag t+1 : gru h-exchange AND the rnn rows consumed by
//                         concat / ctx2-hid (rnn buffer deleted).
//   SCT[b][s]   tag 1   : scores -> ctx2.
//   CTXT[b][k]  tag 1   : ctx2 -> concat.
// GI and w2h are plain floats (launch A completed -> stream-ordered).
#define GRU_NB 256
#define SCO_NB 4096
#define CTX_NB 64
#define CON_NB 128

__global__ __launch_bounds__(256) void k_mega(const float* __restrict__ h0,
    const float* __restrict__ W_hh, const float* __restrict__ b_hh,
    const float* __restrict__ GI, const float* __restrict__ enc,
    const float* __restrict__ w2h, const float* __restrict__ W_c,
    const float* __restrict__ b_c, u64* __restrict__ step,
    u64* __restrict__ sct, u64* __restrict__ ctxt, float* __restrict__ coT,
    float* __restrict__ attn, float* __restrict__ hid) {
  __shared__ __align__(16) char smem[57344];
  const int bx  = blockIdx.x;
  const int tid = threadIdx.x;
  const int lane = tid & 63;

  if (bx < GRU_NB) {
    // =============== GRU role (R5 structure, rnn store dropped) ==========
    __builtin_amdgcn_s_setprio(1);  // keep the serial chain ahead of
                                    // co-resident scores/concat waves
    float4* wlds4 = (float4*)smem;            // 48 KB: 12 W_hh rows
    float (*hs)[kH] = (float (*)[kH])(smem + 49152);  // 2 x 4 KB dbuf
    const int w   = tid >> 6;                 // 0..3
    const int bid = bx;                       // 0..255
    const int j   = bid * 4 + w;

#pragma unroll
    for (int c = 0; c < 12; ++c) {
      const int f    = c * 256 + tid;
      const int row  = f >> 8;
      const int col4 = f & 255;
      const int q    = row >> 2, r = row & 3;
      wlds4[f] = ((const float4*)(W_hh + ((size_t)q * kH + bid * 4 + r) * kH))[col4];
    }

    const float bhr = b_hh[j];
    const float bhz = b_hh[kH + j];
    const float bhn = b_hh[2 * kH + j];

    for (int t = 0; t < kB; ++t) {
      float gir = GI[(size_t)t * kH3 + j];
      float giz = GI[(size_t)t * kH3 + kH + j];
      float gin = GI[(size_t)t * kH3 + 2 * kH + j];
      asm volatile("" :: "v"(gir), "v"(giz), "v"(gin));

      float* hb = hs[t & 1];
      if (t == 0) {
        ((float4*)hb)[tid] = ((const float4*)h0)[tid];
      } else {
        const u64* sb = step + (size_t)(t - 1) * kH;
        const unsigned want = (unsigned)t;
        const int i0 = tid * 4;
        bool done[4] = {false, false, false, false};
        float v[4];
        while (true) {
          bool all = true;
#pragma unroll
          for (int k = 0; k < 4; ++k) {
            if (!done[k]) {
              const u64 x = ld_slot(&sb[i0 + k]);
              if ((unsigned)(x >> 32) == want) {
                v[k] = __uint_as_float((unsigned)x);
                done[k] = true;
              } else {
                all = false;
              }
            }
          }
          if (all) break;
          __builtin_amdgcn_s_sleep(1);
        }
#pragma unroll
        for (int k = 0; k < 4; ++k) hb[i0 + k] = v[k];
      }
      __syncthreads();  // also orders the one-time weight ds_writes at t==0

      float4 hx4[4];
#pragma unroll
      for (int c = 0; c < 4; ++c) hx4[c] = ((const float4*)hb)[lane + 64 * c];

      float d[3];
#pragma unroll
      for (int q = 0; q < 3; ++q) {
        float acc = 0.f;
#pragma unroll
        for (int c = 0; c < 4; ++c) {
          const float4 wq = wlds4[(q * 4 + w) * 256 + lane + 64 * c];
          const float4 h4 = hx4[c];
          acc += wq.x * h4.x + wq.y * h4.y + wq.z * h4.z + wq.w * h4.w;
        }
        d[q] = acc;
      }
#pragma unroll
      for (int q = 0; q < 3; ++q) d[q] = warp_sum(d[q]);

      if (lane == 0) {
        const float ho = hb[j];
        const float r = sigmoidf_(gir + d[0] + bhr);
        const float z = sigmoidf_(giz + d[1] + bhz);
        const float n = tanhf_(gin + r * (d[2] + bhn));
        const float hn = (1.f - z) * n + z * ho;
        st_slot(&step[(size_t)t * kH + j],
                (((u64)(t + 1)) << 32) | __float_as_uint(hn));
      }
      // no trailing barrier: double-buffered hs (see R5 analysis)
    }

  } else if (bx < GRU_NB + SCO_NB) {
    // =============== scores role: sc[b][s] = enc[s][b][:] . w2h ==========
    const int sbid = bx - GRU_NB;
    const int wg = sbid * 4 + (tid >> 6);  // 0..16383
    const int b = wg & 63, s = wg >> 6;
    const float4* ep = (const float4*)(enc + ((size_t)s * kB + b) * kH) + lane * 4;
    const float4* wp = (const float4*)w2h + lane * 4;
    float acc = 0.f;
#pragma unroll
    for (int c = 0; c < 4; ++c) {
      const float4 e = ep[c], wq = wp[c];
      acc += e.x * wq.x + e.y * wq.y + e.z * wq.z + e.w * wq.w;
    }
    acc = warp_sum(acc);
    if (lane == 0)
      st_slot(&sct[(size_t)b * kS + s], (1ULL << 32) | __float_as_uint(acc));

  } else if (bx < GRU_NB + SCO_NB + CTX_NB) {
    // =============== ctx2 role: softmax + context + hid ==================
    // 256 threads. Phase A identical math/order to R5. Phase B: each
    // thread owns h-chunk tid, accumulates 4 s-quarter partials
    // SEQUENTIALLY then adds p0+p1+p2+p3 -> bit-identical to R5's
    // 4-partial LDS tree.
    float* aw = (float*)smem;            // 256 floats
    float* sm = (float*)(smem + 1024);   // 4
    float* ss = (float*)(smem + 1040);   // 4
    const int b = bx - (GRU_NB + SCO_NB);
    const int w = tid >> 6;

    float x;
    {
      const u64* sp = sct + (size_t)b * kS + tid;
      u64 v;
      while ((unsigned)((v = ld_slot(sp)) >> 32) != 1u)
        __builtin_amdgcn_s_sleep(1);
      x = __uint_as_float((unsigned)v);
    }
    float m = warp_max_all(x);
    if (lane == 0) sm[w] = m;
    __syncthreads();
    m = fmaxf(fmaxf(sm[0], sm[1]), fmaxf(sm[2], sm[3]));
    const float e = __expf(x - m);
    float s = warp_sum_all(e);
    if (lane == 0) ss[w] = s;
    __syncthreads();
    s = ss[0] + ss[1] + ss[2] + ss[3];
    const float a = e / s;
    attn[b * kS + tid] = a;   // output (B,1,S)
    aw[tid] = a;
    __syncthreads();

    const float4* encb = (const float4*)enc;
    float4 p[4];
#pragma unroll
    for (int sq = 0; sq < 4; ++sq) {
      float4 acc = make_float4(0.f, 0.f, 0.f, 0.f);
      const int s0 = sq * 64;
#pragma unroll 4
      for (int si = s0; si < s0 + 64; ++si) {
        const float av = aw[si];
        const float4 v = encb[((size_t)si * kB + b) * 256 + tid];
        acc.x += av * v.x; acc.y += av * v.y;
        acc.z += av * v.z; acc.w += av * v.w;
      }
      p[sq] = acc;
    }
    float4 r;
    r.x = p[0].x + p[1].x + p[2].x + p[3].x;
    r.y = p[0].y + p[1].y + p[2].y + p[3].y;
    r.z = p[0].z + p[1].z + p[2].z + p[3].z;
    r.w = p[0].w + p[1].w + p[2].w + p[3].w;
    {
      u64* cb = ctxt + (size_t)b * kH + tid * 4;
      st_slot(&cb[0], (1ULL << 32) | __float_as_uint(r.x));
      st_slot(&cb[1], (1ULL << 32) | __float_as_uint(r.y));
      st_slot(&cb[2], (1ULL << 32) | __float_as_uint(r.z));
      st_slot(&cb[3], (1ULL << 32) | __float_as_uint(r.w));
    }
    // hid copy LAST (polls gru completion) so CTXT publish is not gated
    // on the full scan -> concat pipelines step-by-step behind gru.
    if (b < 4) {
      const u64* hp = step + (size_t)63 * kH + b * 256 + tid;
      u64 v;
      while ((unsigned)((v = ld_slot(hp)) >> 32) != 64u)
        __builtin_amdgcn_s_sleep(1);
      hid[b * 256 + tid] = __uint_as_float((unsigned)v);
    }

  } else {
    // =============== concat role: coT[i][b] = tanh(x_b . W_c[i] + bc) ====
    // x_b = [rnn[b] (STEP row b, tag b+1), ctx[b] (CTXT row b, tag 1)].
    // Paces itself one step behind gru via the STEP tags.
    const int nb = bx - (GRU_NB + SCO_NB + CTX_NB);  // 0..127
    const int wv = tid >> 6;
    const int jcol = lane * 32;
    for (int ii = 0; ii < 2; ++ii) {
      const int i = nb * 8 + wv * 2 + ii;  // 0..1023
      float wreg[32];
      {
        const float4* wp = (const float4*)(W_c + (size_t)i * 2048) + lane * 8;
#pragma unroll
        for (int c = 0; c < 8; ++c) {
          const float4 f = wp[c];
          wreg[c * 4 + 0] = f.x; wreg[c * 4 + 1] = f.y;
          wreg[c * 4 + 2] = f.z; wreg[c * 4 + 3] = f.w;
        }
      }
      const float bc = b_c[i];
      for (int b = 0; b < kB; ++b) {
        const u64* src;
        unsigned want;
        if (jcol < kH) {
          src = step + (size_t)b * kH + jcol;
          want = (unsigned)(b + 1);
        } else {
          src = ctxt + (size_t)b * kH + (jcol - kH);
          want = 1u;
        }
        float acc = 0.f;
#pragma unroll
        for (int g = 0; g < 4; ++g) {
          u64 q[8];
          while (true) {
            bool ok = true;
#pragma unroll
            for (int k = 0; k < 8; ++k) {
              q[k] = ld_slot(&src[g * 8 + k]);
              ok &= ((unsigned)(q[k] >> 32) == want);
            }
            if (ok) break;
            __builtin_amdgcn_s_sleep(1);
          }
#pragma unroll
          for (int k = 0; k < 8; ++k)
            acc += wreg[g * 8 + k] * __uint_as_float((unsigned)q[k]);
        }
        acc = warp_sum(acc);
        if (lane == 0) coT[(size_t)i * kB + b] = tanhf(acc + bc);
      }
    }
  }
}

// ================== Launch C: out[b][v] = coT[:,b].W_out[v] + b_out[v] ====
// 625 blocks x 256 threads; stage 16 W_out rows (64 KB) in LDS with 16
// outstanding coalesced float4 loads/thread; lane=b; broadcast LDS W reads.
__global__ __launch_bounds__(256) void k_out(const float* __restrict__ coT,
    const float* __restrict__ W_out, const float* __restrict__ b_out,
    float* __restrict__ out) {
  __shared__ float wlds[16 * kH];  // 64 KB
  const int v0 = blockIdx.x * 16;
  {
    const float4* src = (const float4*)(W_out + (size_t)v0 * kH);
    float4 tmp[16];
#pragma unroll
    for (int c = 0; c < 16; ++c) tmp[c] = src[threadIdx.x + 256 * c];
    float4* dst = (float4*)wlds;
#pragma unroll
    for (int c = 0; c < 16; ++c) dst[threadIdx.x + 256 * c] = tmp[c];
  }
  __syncthreads();

  const int lane = threadIdx.x & 63;   // = b
  const int w    = threadIdx.x >> 6;   // wave: v-rows 4w..4w+3
  float acc[4] = {0.f, 0.f, 0.f, 0.f};
#pragma unroll 2
  for (int h = 0; h < kH; h += 4) {
    const float x0 = coT[(size_t)(h + 0) * kB + lane];
    const float x1 = coT[(size_t)(h + 1) * kB + lane];
    const float x2 = coT[(size_t)(h + 2) * kB + lane];
    const float x3 = coT[(size_t)(h + 3) * kB + lane];
#pragma unroll
    for (int vi = 0; vi < 4; ++vi) {
      const float4 wq = *(const float4*)&wlds[(w * 4 + vi) * kH + h];
      acc[vi] += wq.x * x0 + wq.y * x1 + wq.z * x2 + wq.w * x3;
    }
  }
  const float4 bq = *(const float4*)(b_out + v0 + w * 4);
  float4 r;
  r.x = acc[0] + bq.x; r.y = acc[1] + bq.y;
  r.z = acc[2] + bq.z; r.w = acc[3] + bq.w;
  *(float4*)&out[(size_t)lane * kV + v0 + w * 4] = r;
}

// ---------------- launcher ----------------
extern "C" void kernel_launch(void* const* d_in, const int* in_sizes, int n_in,
                              void* d_out, int out_size, void* d_ws,
                              size_t ws_size, hipStream_t stream) {
  const int*   seq    = (const int*)  d_in[0];
  const float* h0     = (const float*)d_in[1];
  const float* enc    = (const float*)d_in[2];
  const float* emb    = (const float*)d_in[3];
  const float* W_ih   = (const float*)d_in[4];
  const float* W_hh   = (const float*)d_in[5];
  const float* b_ih   = (const float*)d_in[6];
  const float* b_hh   = (const float*)d_in[7];
  const float* W_attn = (const float*)d_in[8];
  // d_in[9] = b_attn: drops out of softmax (shift invariance)
  const float* v_attn = (const float*)d_in[10];
  const float* W_conc = (const float*)d_in[11];
  const float* b_conc = (const float*)d_in[12];
  const float* W_outp = (const float*)d_in[13];
  const float* b_outp = (const float*)d_in[14];

  float* out      = (float*)d_out;           // (B,V) = 640000
  float* out_hid  = out + 640000;            // (1,1,H) = 1024
  float* out_attn = out + 641024;            // (B,1,S) = 16384

  float* ws = (float*)d_ws;
  u64*   STEP = (u64*)ws;                // 64*1024 u64  = 131072 floats
  float* GI   = ws + 131072;             // 64*3072      = 196608
  float* W2H  = ws + 327680;             // 1024
  u64*   SCT  = (u64*)(ws + 328704);     // 64*256 u64   =  32768 floats
  u64*   CTXT = (u64*)(ws + 361472);     // 64*1024 u64  = 131072 floats
  float* COT  = ws + 492544;             // 1024*64      =  65536 (end 558080)

  k_pre<<<1024, 256, 0, stream>>>(seq, emb, W_ih, b_ih, W_attn, v_attn,
                                  GI, W2H);
  k_mega<<<GRU_NB + SCO_NB + CTX_NB + CON_NB, 256, 0, stream>>>(
      h0, W_hh, b_hh, GI, enc, W2H, W_conc, b_conc,
      STEP, SCT, CTXT, COT, out_attn, out_hid);
  k_out<<<625, 256, 0, stream>>>(COT, W_outp, b_outp, out);
}

// Round 7
// 540.460 us; speedup vs baseline: 2.3778x; 2.3778x over previous
//
#include <hip/hip_runtime.h>
#include <math.h>

// Problem constants
#define kH  1024
#define kB  64
#define kS  256
#define kV  10000
#define kH3 3072

typedef unsigned long long u64;

// ---------------- helpers ----------------
__device__ __forceinline__ float warp_sum(float v) {
#pragma unroll
  for (int off = 32; off > 0; off >>= 1) v += __shfl_down(v, off, 64);
  return v;  // valid on lane 0
}
__device__ __forceinline__ float warp_max_all(float v) {
#pragma unroll
  for (int off = 32; off > 0; off >>= 1) v = fmaxf(v, __shfl_xor(v, off, 64));
  return v;
}
__device__ __forceinline__ float warp_sum_all(float v) {
#pragma unroll
  for (int off = 32; off > 0; off >>= 1) v += __shfl_xor(v, off, 64);
  return v;
}
__device__ __forceinline__ float sigmoidf_(float x) {
  return __fdividef(1.0f, 1.0f + __expf(-x));
}
__device__ __forceinline__ float tanhf_(float x) {
  const float t = __expf(-2.0f * fabsf(x));
  const float r = __fdividef(1.0f - t, 1.0f + t);
  return copysignf(r, x);
}

// ================== Launch A: gi (768 blocks) || w2h (256 blocks) =========
// gi:  GI = emb[seq] @ W_ih^T + b_ih   (independent of w2h)
// w2h: w2h[k] = sum_h v_attn[h] * W_attn[h][H+k]  (softmax shift-invariance
//      kills the h_bc half of cat and b_attn)
__global__ __launch_bounds__(256) void k_pre(const int* __restrict__ seq,
    const float* __restrict__ emb, const float* __restrict__ W_ih,
    const float* __restrict__ b_ih, const float* __restrict__ W_attn,
    const float* __restrict__ v_attn, float* __restrict__ GI,
    float* __restrict__ w2h) {
  __shared__ float4 red[256];
  if (blockIdx.x < 768) {
    // ---- gi role: one wave per output row r, loop over t ----
    const int lane = threadIdx.x & 63;
    const int r = blockIdx.x * 4 + (threadIdx.x >> 6);
    const float4* wp = (const float4*)(W_ih + (size_t)r * kH) + lane * 4;
    const float4 w0 = wp[0], w1 = wp[1], w2 = wp[2], w3 = wp[3];
    const float br = b_ih[r];
    for (int t = 0; t < kB; ++t) {
      const int tok = seq[t];
      const float4* xp = (const float4*)(emb + (size_t)tok * kH) + lane * 4;
      const float4 x0 = xp[0], x1 = xp[1], x2 = xp[2], x3 = xp[3];
      float acc = w0.x*x0.x + w0.y*x0.y + w0.z*x0.z + w0.w*x0.w;
      acc += w1.x*x1.x + w1.y*x1.y + w1.z*x1.z + w1.w*x1.w;
      acc += w2.x*x2.x + w2.y*x2.y + w2.z*x2.z + w2.w*x2.w;
      acc += w3.x*x3.x + w3.y*x3.y + w3.z*x3.z + w3.w*x3.w;
      acc = warp_sum(acc);
      if (lane == 0) GI[(size_t)t * kH3 + r] = acc + br;
    }
  } else {
    // ---- w2h role ----
    const int t  = threadIdx.x;
    const int wb = blockIdx.x - 768;
    const int k0 = kH + wb * 4;  // absolute column in W_attn
    float ax = 0, ay = 0, az = 0, aw = 0;
    for (int h = t; h < kH; h += 256) {
      const float vh = v_attn[h];
      const float4 wq = *(const float4*)(W_attn + (size_t)h * 2048 + k0);
      ax += vh * wq.x; ay += vh * wq.y; az += vh * wq.z; aw += vh * wq.w;
    }
    red[t] = make_float4(ax, ay, az, aw);
    __syncthreads();
    for (int s = 128; s > 0; s >>= 1) {
      if (t < s) {
        const float4 a = red[t], b = red[t + s];
        red[t] = make_float4(a.x + b.x, a.y + b.y, a.z + b.z, a.w + b.w);
      }
      __syncthreads();
    }
    if (t == 0) *(float4*)(w2h + wb * 4) = red[0];
  }
}

// ---------------- Persistent GRU scan (64 sequential steps) ----------------
// R5 structure, byte-identical (R6's mega fusion regressed 2x: co-resident
// polling waves hammered the STEP lines and inflated the serial exchange
// RTT — reverted). 256 blocks x 256 threads, one block per CU. Block bid
// owns h[4*bid..4*bid+3]; wave w owns element j = 4*bid + w. W_hh rows in
// LDS (48 KB; regalloc refuses register residency — R1-R3 evidence).
// Handshake: relaxed agent-scope u64 atomics (tag t+1 | float bits);
// ws poison 0xAAAAAAAA never matches tags 1..64.
__global__ __launch_bounds__(256) void k_gru(const float* __restrict__ h0,
    const float* __restrict__ W_hh, const float* __restrict__ b_hh,
    const float* __restrict__ GI, float* __restrict__ rnn,
    u64* __restrict__ step) {
  __shared__ float4 wlds4[12 * 256];      // 48 KB: 12 rows (3 gates x 4 elems)
  __shared__ __align__(16) float hs[2][kH];  // 8 KB double buffer
  const int tid  = threadIdx.x;           // 0..255
  const int lane = tid & 63;
  const int w    = tid >> 6;              // 0..3
  const int bid  = blockIdx.x;            // 0..255
  const int j    = bid * 4 + w;           // output element owned by this wave

  // ---- stage 12 W_hh rows into LDS (coalesced float4, conflict-free) ----
#pragma unroll
  for (int c = 0; c < 12; ++c) {
    const int f    = c * 256 + tid;       // 0..3071
    const int row  = f >> 8;              // 0..11
    const int col4 = f & 255;             // 0..255
    const int q    = row >> 2, r = row & 3;
    wlds4[f] = ((const float4*)(W_hh + ((size_t)q * kH + bid * 4 + r) * kH))[col4];
  }

  const float bhr = b_hh[j];
  const float bhz = b_hh[kH + j];
  const float bhn = b_hh[2 * kH + j];

  for (int t = 0; t < kB; ++t) {
    // ---- prefetch GI[t] (h-independent): latency hides under the poll ----
    float gir = GI[(size_t)t * kH3 + j];
    float giz = GI[(size_t)t * kH3 + kH + j];
    float gin = GI[(size_t)t * kH3 + 2 * kH + j];
    asm volatile("" :: "v"(gir), "v"(giz), "v"(gin));

    float* hb = hs[t & 1];
    // ---- stage h_prev into LDS (4 slots per thread) ----
    if (t == 0) {
      ((float4*)hb)[tid] = ((const float4*)h0)[tid];
    } else {
      const u64* sb = step + (size_t)(t - 1) * kH;
      const unsigned want = (unsigned)t;  // producer of step t-1 wrote tag t
      const int i0 = tid * 4;
      bool done[4] = {false, false, false, false};
      float v[4];
      while (true) {
        bool all = true;
#pragma unroll
        for (int k = 0; k < 4; ++k) {
          if (!done[k]) {
            const u64 x = __hip_atomic_load(&sb[i0 + k],
                __ATOMIC_RELAXED, __HIP_MEMORY_SCOPE_AGENT);
            if ((unsigned)(x >> 32) == want) {
              v[k] = __uint_as_float((unsigned)x);
              done[k] = true;
            } else {
              all = false;
            }
          }
        }
        if (all) break;
        __builtin_amdgcn_s_sleep(1);
      }
#pragma unroll
      for (int k = 0; k < 4; ++k) hb[i0 + k] = v[k];
    }
    __syncthreads();  // also orders the one-time weight ds_writes at t==0

    // ---- hx4[c] = h_prev float4 slice (conflict-free b128 reads) ----
    float4 hx4[4];
#pragma unroll
    for (int c = 0; c < 4; ++c) hx4[c] = ((const float4*)hb)[lane + 64 * c];

    // ---- d[q] = W_hh[q*kH+j][:] . h_prev  (weights from LDS) ----
    float d[3];
#pragma unroll
    for (int q = 0; q < 3; ++q) {
      float acc = 0.f;
#pragma unroll
      for (int c = 0; c < 4; ++c) {
        const float4 wq = wlds4[(q * 4 + w) * 256 + lane + 64 * c];
        const float4 h4 = hx4[c];
        acc += wq.x * h4.x + wq.y * h4.y + wq.z * h4.z + wq.w * h4.w;
      }
      d[q] = acc;
    }
#pragma unroll
    for (int q = 0; q < 3; ++q) d[q] = warp_sum(d[q]);

    if (lane == 0) {
      const float ho = hb[j];  // exact h_prev from LDS
      const float r = sigmoidf_(gir + d[0] + bhr);
      const float z = sigmoidf_(giz + d[1] + bhz);
      const float n = tanhf_(gin + r * (d[2] + bhn));
      const float hn = (1.f - z) * n + z * ho;
      rnn[(size_t)t * kH + j] = hn;  // for downstream kernels
      __hip_atomic_store(&step[(size_t)t * kH + j],
                         (((u64)(t + 1)) << 32) | __float_as_uint(hn),
                         __ATOMIC_RELAXED, __HIP_MEMORY_SCOPE_AGENT);
    }
    // no trailing barrier: double-buffered hs (see R5 analysis)
  }
}

// ========== Launch C: fused scores + softmax + context + hid =============
// 64 blocks (one per b) x 1024 threads (16 waves). Replaces k_scores +
// k_ctx2 WITHOUT cross-block handshakes: block b computes its own 256
// scores (wave w does s = w*16..w*16+15; dot order bit-identical to the
// old k_scores), then softmax (bit-identical to old k_softmax) and context
// (bit-identical to old 1024-thread k_ctx2 4-partial tree).
__global__ __launch_bounds__(1024) void k_att(const float* __restrict__ enc,
    const float* __restrict__ w2h, const float* __restrict__ rnn,
    float* __restrict__ attn, float* __restrict__ ctx,
    float* __restrict__ hid) {
  __shared__ float scl[kS];
  __shared__ float sm[4], ss[4];
  __shared__ float4 part4[1024];  // 16 KB
  const int b = blockIdx.x, tid = threadIdx.x;
  const int lane = tid & 63, w = tid >> 6;  // w: 0..15

  // ---- Phase 1: scores ----
  {
    const float4* wp = (const float4*)w2h + lane * 4;
    const float4 wq0 = wp[0], wq1 = wp[1], wq2 = wp[2], wq3 = wp[3];
    for (int k = 0; k < 16; ++k) {
      const int s = w * 16 + k;
      const float4* ep =
          (const float4*)(enc + ((size_t)s * kB + b) * kH) + lane * 4;
      const float4 e0 = ep[0], e1 = ep[1], e2 = ep[2], e3 = ep[3];
      float acc = e0.x*wq0.x + e0.y*wq0.y + e0.z*wq0.z + e0.w*wq0.w;
      acc += e1.x*wq1.x + e1.y*wq1.y + e1.z*wq1.z + e1.w*wq1.w;
      acc += e2.x*wq2.x + e2.y*wq2.y + e2.z*wq2.z + e2.w*wq2.w;
      acc += e3.x*wq3.x + e3.y*wq3.y + e3.z*wq3.z + e3.w*wq3.w;
      acc = warp_sum(acc);
      if (lane == 0) scl[s] = acc;
    }
  }
  __syncthreads();

  // ---- Phase 2: softmax over 256 scores (waves 0..3 only) ----
  float x = 0.f, e = 0.f;
  if (tid < kS) {
    x = scl[tid];
    const float m = warp_max_all(x);
    if (lane == 0) sm[w] = m;
  }
  __syncthreads();
  if (tid < kS) {
    const float m = fmaxf(fmaxf(sm[0], sm[1]), fmaxf(sm[2], sm[3]));
    e = __expf(x - m);
    const float s = warp_sum_all(e);
    if (lane == 0) ss[w] = s;
  }
  __syncthreads();
  if (tid < kS) {
    const float s = ss[0] + ss[1] + ss[2] + ss[3];
    const float a = e / s;
    attn[b * kS + tid] = a;   // output (B,1,S)
    scl[tid] = a;             // reuse as weight array (all reads of raw
                              // scores happened before the first barrier)
  }
  if (b < 4 && tid < kS) {    // hidden output copy (independent)
    hid[b * kS + tid] = rnn[63 * kH + b * kS + tid];
  }
  __syncthreads();

  // ---- Phase 3: context; thread owns h-chunk hc within s-quarter sq ----
  const int hc = tid & 255;
  const int sq = tid >> 8;    // 0..3
  const float4* encb = (const float4*)enc;
  float4 acc = make_float4(0.f, 0.f, 0.f, 0.f);
  const int s0 = sq * 64;
#pragma unroll 4
  for (int s = s0; s < s0 + 64; ++s) {
    const float a = scl[s];
    const float4 v = encb[((size_t)s * kB + b) * 256 + hc];
    acc.x += a * v.x; acc.y += a * v.y; acc.z += a * v.z; acc.w += a * v.w;
  }
  part4[tid] = acc;
  __syncthreads();
  if (tid < 256) {
    const float4 p0 = part4[tid], p1 = part4[tid + 256];
    const float4 p2 = part4[tid + 512], p3 = part4[tid + 768];
    float4 r;
    r.x = p0.x + p1.x + p2.x + p3.x;
    r.y = p0.y + p1.y + p2.y + p3.y;
    r.z = p0.z + p1.z + p2.z + p3.z;
    r.w = p0.w + p1.w + p2.w + p3.w;
    ((float4*)(ctx + (size_t)b * kH))[tid] = r;
  }
}

// ---------------- coT[i][b] = tanh([rnn,ctx][b] . W_concat[i] + b_c[i]) ----------------
// b-loop split 4 ways (1024 blocks) for TLP; W_c rows re-read 4x (L2).
__global__ __launch_bounds__(256) void k_concat(const float* __restrict__ rnn,
    const float* __restrict__ ctx, const float* __restrict__ W_c,
    const float* __restrict__ b_c, float* __restrict__ coT) {
  const int lane = threadIdx.x & 63;
  const int iq = blockIdx.x >> 2;                 // 0..255
  const int bq = blockIdx.x & 3;                  // 0..3
  const int i  = iq * 4 + (threadIdx.x >> 6);     // 0..1023
  float wreg[32];
  {
    const float4* wp = (const float4*)(W_c + (size_t)i * 2048) + lane * 8;
#pragma unroll
    for (int c = 0; c < 8; ++c) {
      const float4 f = wp[c];
      wreg[c * 4 + 0] = f.x; wreg[c * 4 + 1] = f.y;
      wreg[c * 4 + 2] = f.z; wreg[c * 4 + 3] = f.w;
    }
  }
  const float bc = b_c[i];
  const int jcol = lane * 32;
  const float* xbase = (jcol < kH) ? (rnn + jcol) : (ctx + (jcol - kH));
  for (int b = bq * 16; b < bq * 16 + 16; ++b) {
    const float* xr = xbase + (size_t)b * kH;
    float acc = 0.f;
#pragma unroll
    for (int c = 0; c < 8; ++c) {
      const float4 x = *(const float4*)(xr + c * 4);
      acc += wreg[c * 4 + 0] * x.x + wreg[c * 4 + 1] * x.y +
             wreg[c * 4 + 2] * x.z + wreg[c * 4 + 3] * x.w;
    }
    acc = warp_sum(acc);
    if (lane == 0) coT[(size_t)i * kB + b] = tanhf(acc + bc);
  }
}

// ---------------- out[b][v] = coT[:,b] . W_out[v] + b_out[v] ----------------
// 625 blocks x 256 threads; stage 16 W_out rows (64 KB) in LDS with 16
// outstanding coalesced float4 loads/thread; lane=b; broadcast LDS W reads.
__global__ __launch_bounds__(256) void k_out(const float* __restrict__ coT,
    const float* __restrict__ W_out, const float* __restrict__ b_out,
    float* __restrict__ out) {
  __shared__ float wlds[16 * kH];  // 64 KB
  const int v0 = blockIdx.x * 16;
  {
    const float4* src = (const float4*)(W_out + (size_t)v0 * kH);
    float4 tmp[16];
#pragma unroll
    for (int c = 0; c < 16; ++c) tmp[c] = src[threadIdx.x + 256 * c];
    float4* dst = (float4*)wlds;
#pragma unroll
    for (int c = 0; c < 16; ++c) dst[threadIdx.x + 256 * c] = tmp[c];
  }
  __syncthreads();

  const int lane = threadIdx.x & 63;   // = b
  const int w    = threadIdx.x >> 6;   // wave: v-rows 4w..4w+3
  float acc[4] = {0.f, 0.f, 0.f, 0.f};
#pragma unroll 2
  for (int h = 0; h < kH; h += 4) {
    const float x0 = coT[(size_t)(h + 0) * kB + lane];
    const float x1 = coT[(size_t)(h + 1) * kB + lane];
    const float x2 = coT[(size_t)(h + 2) * kB + lane];
    const float x3 = coT[(size_t)(h + 3) * kB + lane];
#pragma unroll
    for (int vi = 0; vi < 4; ++vi) {
      const float4 wq = *(const float4*)&wlds[(w * 4 + vi) * kH + h];
      acc[vi] += wq.x * x0 + wq.y * x1 + wq.z * x2 + wq.w * x3;
    }
  }
  const float4 bq = *(const float4*)(b_out + v0 + w * 4);
  float4 r;
  r.x = acc[0] + bq.x; r.y = acc[1] + bq.y;
  r.z = acc[2] + bq.z; r.w = acc[3] + bq.w;
  *(float4*)&out[(size_t)lane * kV + v0 + w * 4] = r;
}

// ---------------- launcher ----------------
extern "C" void kernel_launch(void* const* d_in, const int* in_sizes, int n_in,
                              void* d_out, int out_size, void* d_ws,
                              size_t ws_size, hipStream_t stream) {
  const int*   seq    = (const int*)  d_in[0];
  const float* h0     = (const float*)d_in[1];
  const float* enc    = (const float*)d_in[2];
  const float* emb    = (const float*)d_in[3];
  const float* W_ih   = (const float*)d_in[4];
  const float* W_hh   = (const float*)d_in[5];
  const float* b_ih   = (const float*)d_in[6];
  const float* b_hh   = (const float*)d_in[7];
  const float* W_attn = (const float*)d_in[8];
  // d_in[9] = b_attn: drops out of softmax (shift invariance)
  const float* v_attn = (const float*)d_in[10];
  const float* W_conc = (const float*)d_in[11];
  const float* b_conc = (const float*)d_in[12];
  const float* W_outp = (const float*)d_in[13];
  const float* b_outp = (const float*)d_in[14];

  float* out      = (float*)d_out;           // (B,V) = 640000
  float* out_hid  = out + 640000;            // (1,1,H) = 1024
  float* out_attn = out + 641024;            // (B,1,S) = 16384

  float* ws = (float*)d_ws;
  float* GI   = ws;                      // 64*3072     = 196608
  float* RNN  = ws + 196608;             // 64*1024     =  65536
  u64*   STEP = (u64*)(ws + 262144);     // 64*1024 u64 = 131072 floats
  float* W2H  = ws + 393216;             // 1024
  float* CTX  = ws + 394240;             // 64*1024     =  65536
  float* COT  = ws + 459776;             // 1024*64     =  65536 (end 525312)

  k_pre<<<1024, 256, 0, stream>>>(seq, emb, W_ih, b_ih, W_attn, v_attn,
                                  GI, W2H);
  k_gru<<<256, 256, 0, stream>>>(h0, W_hh, b_hh, GI, RNN, STEP);
  k_att<<<64, 1024, 0, stream>>>(enc, W2H, RNN, out_attn, CTX, out_hid);
  k_concat<<<1024, 256, 0, stream>>>(RNN, CTX, W_conc, b_conc, COT);
  k_out<<<625, 256, 0, stream>>>(COT, W_outp, b_outp, out);
}